// Round 2
// baseline (1284.967 us; speedup 1.0000x reference)
//
#include <hip/hip_runtime.h>

// Inverse-CDF categorical sampler: out[row] = #{ v : cumsum(p[row])[v] < rng[row] }
// B*T = 8192 rows, V = 32000.
//
// Monotone-CDF decomposition: each of 256 threads owns a contiguous 128-float
// chunk (250 active). Phase A streams chunk sums (order-agnostic, full MLP,
// zero barriers). One block scan of the 250 chunk sums locates the unique
// crossing chunk (E < r <= incl); only that thread replays its 128 floats
// (L1-hot re-read) for the exact inner count. E := shfl_up(incl,1) makes
// interval boundaries bit-exact between neighbors -> no gaps, no missed write.

constexpr int V = 32000;
constexpr int CHUNK = 128;            // floats per thread-chunk (512 B, line-aligned)
constexpr int NCHUNK = V / CHUNK;     // 250 chunks per row

__global__ __launch_bounds__(256) void sampler_kernel(
    const float* __restrict__ p,
    const float* __restrict__ rng,
    int* __restrict__ out)
{
    const int row  = blockIdx.x;
    const int tid  = threadIdx.x;
    const int lane = tid & 63;
    const int wave = tid >> 6;

    const float r = rng[row];
    const float* prow = p + (size_t)row * V;
    const bool active = (tid < NCHUNK);

    __shared__ float wsum[4];

    // ---- Phase A: contiguous-chunk sum, 32x float4 strided-coalesced ----
    float S = 0.0f;
    if (active) {
        const float4* c4 = reinterpret_cast<const float4*>(prow + tid * CHUNK);
        float s0 = 0.f, s1 = 0.f, s2 = 0.f, s3 = 0.f;
        #pragma unroll 2
        for (int j = 0; j < 32; j += 4) {
            float4 a = c4[j+0];
            float4 b = c4[j+1];
            float4 c = c4[j+2];
            float4 d = c4[j+3];
            s0 += (a.x + a.y) + (a.z + a.w);
            s1 += (b.x + b.y) + (b.z + b.w);
            s2 += (c.x + c.y) + (c.z + c.w);
            s3 += (d.x + d.y) + (d.z + d.w);
        }
        S = (s0 + s1) + (s2 + s3);
    }

    // ---- one block-level inclusive scan of chunk sums ----
    float scan = S;
    #pragma unroll
    for (int off = 1; off < 64; off <<= 1) {
        float n = __shfl_up(scan, off, 64);
        if (lane >= off) scan += n;
    }
    if (lane == 63) wsum[wave] = scan;
    __syncthreads();

    // serial accumulation in wave order -> waveBase_w == incl(lane63, w-1) exactly
    float waveBase = 0.0f;
    #pragma unroll
    for (int w = 0; w < 4; ++w)
        if (w < wave) waveBase += wsum[w];

    const float incl = waveBase + scan;        // inclusive prefix of chunk sums
    float E = __shfl_up(incl, 1, 64);          // exclusive = neighbor's inclusive (exact)
    if (lane == 0) E = waveBase;

    // ---- Phase B: unique crossing chunk resolves the inner count ----
    if (active && (r <= incl) && (E < r || tid == 0)) {
        const float4* c4 = reinterpret_cast<const float4*>(prow + tid * CHUNK);
        float run = E;
        int cnt = 0;
        #pragma unroll 4
        for (int j = 0; j < 32; ++j) {
            float4 x = c4[j];
            run += x.x; cnt += (run < r);
            run += x.y; cnt += (run < r);
            run += x.z; cnt += (run < r);
            run += x.w; cnt += (run < r);
        }
        out[row] = tid * CHUNK + cnt;
    }
    // r beyond total probability mass -> all V categories counted
    if (tid == NCHUNK - 1 && incl < r) {
        out[row] = V;
    }
}

extern "C" void kernel_launch(void* const* d_in, const int* in_sizes, int n_in,
                              void* d_out, int out_size, void* d_ws, size_t ws_size,
                              hipStream_t stream) {
    const float* p   = (const float*)d_in[0];
    const float* rng = (const float*)d_in[1];
    int* out = (int*)d_out;
    const int rows = in_sizes[1];   // B*T = 8192
    sampler_kernel<<<rows, 256, 0, stream>>>(p, rng, out);
}